// Round 1
// baseline (691.403 us; speedup 1.0000x reference)
//
#include <hip/hip_runtime.h>
#include <math.h>
#include <stdint.h>

// Problem constants (B,H,W,K,J) = (8,256,256,100,17)
#define HW    65536
#define BATCH 8
#define NJ    17
#define TOPK  100
#define NCH   144   // 8 hm channels + 8*17 hm_hp channels

// d_out float offsets (concatenated outputs, all f32)
#define OFF_HM   0ull
#define OFF_WH   524288ull
#define OFF_HPS  1572864ull
#define OFF_REG  19398656ull
#define OFF_HMHP 20447232ull
#define OFF_HPO  29360128ull
#define OFF_DET  30408704ull   // 8*100*40 = 32000 floats

__device__ __forceinline__ float sigmoidf_(float x) {
    return 1.0f / (1.0f + expf(-x));
}

// ---------------------------------------------------------------------------
// Kernel A: elementwise — sigmoid(hm), copy wh, copy hps, copy reg,
// sigmoid(hm_hp), copy hp_offset. One float4 per thread.
// vec4 segment boundaries:
//   hm:131072 | wh:+262144 | hps:+4456448 | reg:+262144 | hm_hp:+2228224 | hpo:+262144
// ---------------------------------------------------------------------------
__global__ __launch_bounds__(256) void ew_kernel(
    const float4* __restrict__ in0, const float4* __restrict__ in1,
    const float4* __restrict__ in2, const float4* __restrict__ in3,
    const float4* __restrict__ in4, const float4* __restrict__ in5,
    float4* __restrict__ out)
{
    const int a0 = 131072, a1 = 393216, a2 = 4849664, a3 = 5111808,
              a4 = 7340032, a5 = 7602176;
    int i = blockIdx.x * 256 + threadIdx.x;
    if (i >= a5) return;
    float4 v;
    if (i < a0) {
        v = in0[i];
        v.x = sigmoidf_(v.x); v.y = sigmoidf_(v.y);
        v.z = sigmoidf_(v.z); v.w = sigmoidf_(v.w);
    } else if (i < a1) {
        v = in1[i - a0];
    } else if (i < a2) {
        v = in2[i - a1];
    } else if (i < a3) {
        v = in3[i - a2];
    } else if (i < a4) {
        v = in4[i - a3];
        v.x = sigmoidf_(v.x); v.y = sigmoidf_(v.y);
        v.z = sigmoidf_(v.z); v.w = sigmoidf_(v.w);
    } else {
        v = in5[i - a4];
    }
    out[i] = v;
}

// ---------------------------------------------------------------------------
// Kernel NMS: 3x3 local-max mask on sigmoid maps (read from d_out), write
// NMS'd scores (value if center >= all neighbors else 0) to workspace.
// ---------------------------------------------------------------------------
__global__ __launch_bounds__(256) void nms_kernel(
    const float* __restrict__ sig_hm, const float* __restrict__ sig_hmhp,
    float* __restrict__ nmsbuf)
{
    int c = blockIdx.y;
    int pix = blockIdx.x * 256 + threadIdx.x;
    const float* src = (c < 8) ? (sig_hm + (size_t)c * HW)
                               : (sig_hmhp + (size_t)(c - 8) * HW);
    float ce = src[pix];
    int y = pix >> 8, x = pix & 255;
    bool xm = x > 0, xp = x < 255;
    float m = -INFINITY;
    if (y > 0) {
        const float* r = src + pix - 256;
        if (xm) m = fmaxf(m, r[-1]);
        m = fmaxf(m, r[0]);
        if (xp) m = fmaxf(m, r[1]);
    }
    if (xm) m = fmaxf(m, src[pix - 1]);
    if (xp) m = fmaxf(m, src[pix + 1]);
    if (y < 255) {
        const float* r = src + pix + 256;
        if (xm) m = fmaxf(m, r[-1]);
        m = fmaxf(m, r[0]);
        if (xp) m = fmaxf(m, r[1]);
    }
    nmsbuf[(size_t)c * HW + pix] = (ce >= m) ? ce : 0.0f;
}

// ---------------------------------------------------------------------------
// Kernel B: exact top-100 per channel via 48-bit-key radix select.
// key = (sortable_float(score) << 16) | (65535 - pix)  — descending value,
// ties broken toward lower pix (matches jax.lax.top_k). Scores are sigmoid
// outputs (>0) or exactly 0 (suppressed) — zeros are skipped; #positives
// (~HW/9) >> 100 so the 100th-largest is always positive.
// Then: hm channels (c<8) -> write det bbox/score/cls + stash inds;
//       hm_hp channels   -> apply hp_offset gather + threshold, stash cands.
// ---------------------------------------------------------------------------
template <bool MAT>
__global__ __launch_bounds__(256) void topk_kernel(
    const float* __restrict__ nmsbuf,
    const float* __restrict__ sig_hm, const float* __restrict__ sig_hmhp,
    const float* __restrict__ reg, const float* __restrict__ wh,
    const float* __restrict__ hpo,
    float* __restrict__ det, int* __restrict__ ind_hm,
    float* __restrict__ cx, float* __restrict__ cy, float* __restrict__ cs)
{
    __shared__ unsigned int hist[4096];
    __shared__ unsigned int chunk[256];
    __shared__ unsigned long long keys[128];
    __shared__ unsigned long long s_prefix;
    __shared__ int s_krem;
    __shared__ int s_cnt;

    const int c = blockIdx.x;
    const int tid = threadIdx.x;
    const float* nsrc = MAT ? (nmsbuf + (size_t)c * HW) : nullptr;
    const float* sig = (c < 8) ? (sig_hm + (size_t)c * HW)
                               : (sig_hmhp + (size_t)(c - 8) * HW);

    auto score_at = [&](int e) -> float {
        if (MAT) return nsrc[e];
        float ce = sig[e];
        int y = e >> 8, x = e & 255;
        bool xm = x > 0, xp = x < 255;
        float m = -INFINITY;
        if (y > 0) {
            if (xm) m = fmaxf(m, sig[e - 257]);
            m = fmaxf(m, sig[e - 256]);
            if (xp) m = fmaxf(m, sig[e - 255]);
        }
        if (xm) m = fmaxf(m, sig[e - 1]);
        if (xp) m = fmaxf(m, sig[e + 1]);
        if (y < 255) {
            if (xm) m = fmaxf(m, sig[e + 255]);
            m = fmaxf(m, sig[e + 256]);
            if (xp) m = fmaxf(m, sig[e + 257]);
        }
        return (ce >= m) ? ce : 0.0f;
    };

    if (tid == 0) { s_prefix = 0ULL; s_krem = TOPK; s_cnt = 0; }

    unsigned long long prefix = 0;
    int krem = TOPK;

    for (int pass = 0; pass < 4; ++pass) {
        const int shift = 36 - 12 * pass;
        for (int i = tid; i < 4096; i += 256) hist[i] = 0;
        __syncthreads();
        for (int e = tid; e < HW; e += 256) {
            float v = score_at(e);
            if (v > 0.0f) {
                unsigned int su = __float_as_uint(v) | 0x80000000u;
                unsigned long long key =
                    ((unsigned long long)su << 16) | (unsigned long long)(65535 - e);
                if ((key >> (shift + 12)) == prefix)
                    atomicAdd(&hist[(unsigned int)(key >> shift) & 0xFFFu], 1u);
            }
        }
        __syncthreads();
        unsigned int csum = 0;
#pragma unroll
        for (int i2 = 0; i2 < 16; ++i2) csum += hist[tid * 16 + i2];
        chunk[tid] = csum;
        __syncthreads();
        if (tid == 0) {
            int cum = 0, sel = 0;
            for (int tc = 255; tc >= 0; --tc) {
                if (cum + (int)chunk[tc] >= krem) {
                    for (int d = tc * 16 + 15;; --d) {
                        cum += (int)hist[d];
                        if (cum >= krem) {
                            sel = d;
                            s_krem = krem - (cum - (int)hist[d]);
                            break;
                        }
                    }
                    break;
                }
                cum += (int)chunk[tc];
            }
            s_prefix = (s_prefix << 12) | (unsigned long long)sel;
        }
        __syncthreads();
        prefix = s_prefix;
        krem = s_krem;
    }

    const unsigned long long T = prefix;  // exact 100th-largest key

    // Collect: exactly 100 distinct keys >= T.
    for (int e = tid; e < HW; e += 256) {
        float v = score_at(e);
        if (v > 0.0f) {
            unsigned int su = __float_as_uint(v) | 0x80000000u;
            unsigned long long key =
                ((unsigned long long)su << 16) | (unsigned long long)(65535 - e);
            if (key >= T) {
                int pos = atomicAdd(&s_cnt, 1);
                if (pos < 128) keys[pos] = key;
            }
        }
    }
    __syncthreads();
    int cnt = s_cnt;
    if (cnt > 128) cnt = 128;
    if (tid < 128 && tid >= cnt) keys[tid] = 0ULL;

    // Bitonic sort 128 keys descending.
    for (int ksz = 2; ksz <= 128; ksz <<= 1) {
        for (int jj = ksz >> 1; jj > 0; jj >>= 1) {
            __syncthreads();
            if (tid < 128) {
                int ixj = tid ^ jj;
                if (ixj > tid) {
                    unsigned long long a = keys[tid], b2 = keys[ixj];
                    bool up = ((tid & ksz) == 0);
                    if (up ? (a < b2) : (a > b2)) {
                        keys[tid] = b2;
                        keys[ixj] = a;
                    }
                }
            }
        }
    }
    __syncthreads();

    if (tid < TOPK) {
        unsigned long long key = keys[tid];
        float val = __uint_as_float((unsigned int)(key >> 16) & 0x7FFFFFFFu);
        int pix = 65535 - (int)(key & 0xFFFFull);
        if (c < 8) {
            int b = c;
            ind_hm[b * TOPK + tid] = pix;
            float xs0 = (float)(pix & 255), ys0 = (float)(pix >> 8);
            float r0 = reg[((size_t)b * 2 + 0) * HW + pix];
            float r1 = reg[((size_t)b * 2 + 1) * HW + pix];
            float w0 = wh[((size_t)b * 2 + 0) * HW + pix];
            float w1 = wh[((size_t)b * 2 + 1) * HW + pix];
            float xs = xs0 + r0, ys = ys0 + r1;
            float* row = det + ((size_t)b * TOPK + tid) * 40;
            row[0] = xs - w0 * 0.5f;
            row[1] = ys - w1 * 0.5f;
            row[2] = xs + w0 * 0.5f;
            row[3] = ys + w1 * 0.5f;
            row[4] = val;
            row[39] = 0.0f;   // cls (C=1 -> always 0)
        } else {
            int cc = c - 8, b = cc / NJ, j = cc % NJ;
            float xs = (float)(pix & 255), ys = (float)(pix >> 8);
            float o0 = hpo[((size_t)b * 2 + 0) * HW + pix];
            float o1 = hpo[((size_t)b * 2 + 1) * HW + pix];
            bool m = val > 0.1f;
            int idx = (b * NJ + j) * TOPK + tid;
            cs[idx] = m ? val : -1.0f;
            cx[idx] = m ? (xs + o0) : -10000.0f;
            cy[idx] = m ? (ys + o1) : -10000.0f;
        }
    }
}

// ---------------------------------------------------------------------------
// Kernel C: per (b,j) block — for each detection k: gather kp regression,
// nearest hm_hp candidate (strict-< keeps first index, matching argmin),
// bad-check against bbox, write kps to detection rows.
// ---------------------------------------------------------------------------
__global__ __launch_bounds__(128) void assign_kernel(
    const float* __restrict__ hps, const int* __restrict__ ind_hm,
    const float* __restrict__ cx, const float* __restrict__ cy,
    const float* __restrict__ cs, float* __restrict__ det)
{
    __shared__ float sx[TOPK], sy[TOPK], ss[TOPK];
    __shared__ float sl[TOPK], st[TOPK], sr[TOPK], sb[TOPK];
    __shared__ float x0[TOPK], y0[TOPK];
    __shared__ int sind[TOPK];

    int b = blockIdx.x / NJ, j = blockIdx.x % NJ;
    int k = threadIdx.x;
    if (k < TOPK) {
        int base = (b * NJ + j) * TOPK + k;
        sx[k] = cx[base]; sy[k] = cy[base]; ss[k] = cs[base];
        const float* row = det + ((size_t)b * TOPK + k) * 40;
        sl[k] = row[0]; st[k] = row[1]; sr[k] = row[2]; sb[k] = row[3];
        int ind = ind_hm[b * TOPK + k];
        sind[k] = ind;
        x0[k] = (float)(ind & 255);
        y0[k] = (float)(ind >> 8);
    }
    __syncthreads();
    if (k < TOPK) {
        int ind = sind[k];
        float kx = hps[((size_t)b * 34 + 2 * j + 0) * HW + ind] + x0[k];
        float ky = hps[((size_t)b * 34 + 2 * j + 1) * HW + ind] + y0[k];
        float best = INFINITY;
        int bi = 0;
        for (int cand = 0; cand < TOPK; ++cand) {
            float dx = kx - sx[cand], dy = ky - sy[cand];
            float d = sqrtf(dx * dx + dy * dy);
            if (d < best) { best = d; bi = cand; }
        }
        float hx = sx[bi], hy = sy[bi], hs = ss[bi];
        float w = sr[k] - sl[k], h = sb[k] - st[k];
        bool bad = (hx < sl[k]) || (hx > sr[k]) || (hy < st[k]) || (hy > sb[k]) ||
                   (hs < 0.1f) || (best > fmaxf(h, w) * 0.3f);
        float ox = bad ? kx : hx;
        float oy = bad ? ky : hy;
        float* orow = det + ((size_t)b * TOPK + k) * 40;
        orow[5 + 2 * j] = ox;
        orow[6 + 2 * j] = oy;
    }
}

// ---------------------------------------------------------------------------
extern "C" void kernel_launch(void* const* d_in, const int* in_sizes, int n_in,
                              void* d_out, int out_size, void* d_ws, size_t ws_size,
                              hipStream_t stream) {
    const float* hm    = (const float*)d_in[0];
    const float* wh    = (const float*)d_in[1];
    const float* hps   = (const float*)d_in[2];
    const float* reg   = (const float*)d_in[3];
    const float* hm_hp = (const float*)d_in[4];
    const float* hpo   = (const float*)d_in[5];
    float* out = (float*)d_out;

    // Workspace layout (all offsets 16B-aligned):
    //   ind_hm : int  [8*100]              @ 0       (3200 B)
    //   cx     : f32  [8*17*100]           @ 3200    (54400 B)
    //   cy     : f32  [8*17*100]           @ 57600
    //   cs     : f32  [8*17*100]           @ 112000
    //   nmsbuf : f32  [144*65536]          @ 166400  (37.75 MB) — optional
    char* ws = (char*)d_ws;
    int*   ind_hm = (int*)ws;
    float* cx = (float*)(ws + 3200);
    float* cy = (float*)(ws + 57600);
    float* cs = (float*)(ws + 112000);
    float* nmsbuf = (float*)(ws + 166400);
    const size_t need_mat = 166400ull + (size_t)NCH * HW * 4ull;
    const bool mat = (ws_size >= need_mat);

    ew_kernel<<<29696, 256, 0, stream>>>(
        (const float4*)hm, (const float4*)wh, (const float4*)hps,
        (const float4*)reg, (const float4*)hm_hp, (const float4*)hpo,
        (float4*)out);

    const float* sig_hm   = out + OFF_HM;
    const float* sig_hmhp = out + OFF_HMHP;
    float* det = out + OFF_DET;

    if (mat) {
        nms_kernel<<<dim3(HW / 256, NCH), 256, 0, stream>>>(sig_hm, sig_hmhp, nmsbuf);
        topk_kernel<true><<<NCH, 256, 0, stream>>>(
            nmsbuf, sig_hm, sig_hmhp, reg, wh, hpo, det, ind_hm, cx, cy, cs);
    } else {
        topk_kernel<false><<<NCH, 256, 0, stream>>>(
            nullptr, sig_hm, sig_hmhp, reg, wh, hpo, det, ind_hm, cx, cy, cs);
    }

    assign_kernel<<<BATCH * NJ, 128, 0, stream>>>(hps, ind_hm, cx, cy, cs, det);
}